// Round 12
// baseline (190.494 us; speedup 1.0000x reference)
//
#include <hip/hip_runtime.h>
#include <math.h>

// RESUS_NN_2327872274812: Q=8192, S=30, D=512.  FP32-exact, deterministic.
// r11 skeleton (pinned q/w regs + seg-padded LDS support) with the hot-loop
// shuffles REMOVED: every __shfl emits a ds op + s_waitcnt lgkmcnt(0), which
// drains the whole ds_read queue -> per-sl serialization (r10/r11 ceiling).
// Instead each thread writes its (sc,sq) partial with ONE ds_write_b64 to
// praw[sl][ql][dseg]; reduction over dseg is a separate per-pass phase.
// 3 passes x 10 support rows -> LDS 52.6 KB -> 3 blocks/CU (3 waves/SIMD).
// thread = (ql 0..15, dseg 0..15): query ql, 32-float d-slice dseg.

#define QN 8192
#define SN 30
#define DN 512
#define BLK 256
#define QT 16            // queries per block
#define SCHUNK 10        // support rows per pass
#define NPASS 3
#define SROW 572         // floats per LDS support row (15 segs... 16 segs*36 - 4 + 32; 16*36=576? keep 572: 15*36+32? dseg max 15 -> 15*36+36=576 needed) 
#undef SROW
#define SROW 580         // 16 segs * 36 floats + 4 slack
#define PRW 17           // praw dseg-dim stride (float2)
#define PSTR 31          // final part row stride (float2)

__global__ __launch_bounds__(BLK, 3)
void resus_one(const float* __restrict__ query,      // [Q][D]
               const float* __restrict__ support,    // [S][D]
               const float* __restrict__ support_y,  // [S]
               const float* __restrict__ support_pr, // [S]
               const float* __restrict__ query_pr,   // [Q]
               const float* __restrict__ fc1_w,      // [D]
               const float* __restrict__ adj_scale,  // [30]
               const float* __restrict__ adj_bias,   // [30]
               const int*   __restrict__ num_samples,// [1]
               float* __restrict__ out)              // [2*Q]
{
    __shared__ float  sp[SCHUNK * SROW];        // 23,200 B
    __shared__ float2 praw[SCHUNK * QT * PRW];  // 21,760 B
    __shared__ float2 part[QT * PSTR];          //  3,968 B   total 48,928 B

    const int tid  = threadIdx.x;
    const int ql   = tid & 15;                // query slot
    const int dseg = tid >> 4;                // 32-float d-segment
    const int q    = blockIdx.x * QT + ql;

    // ---- one-time: q + w slices into named regs, then PIN (worked in r11) ----
    const float* qp = query + (size_t)q * DN + dseg * 32;
    float4 q0 = *reinterpret_cast<const float4*>(qp +  0);
    float4 q1 = *reinterpret_cast<const float4*>(qp +  4);
    float4 q2 = *reinterpret_cast<const float4*>(qp +  8);
    float4 q3 = *reinterpret_cast<const float4*>(qp + 12);
    float4 q4 = *reinterpret_cast<const float4*>(qp + 16);
    float4 q5 = *reinterpret_cast<const float4*>(qp + 20);
    float4 q6 = *reinterpret_cast<const float4*>(qp + 24);
    float4 q7 = *reinterpret_cast<const float4*>(qp + 28);
    const float* wp = fc1_w + dseg * 32;
    float4 w0 = *reinterpret_cast<const float4*>(wp +  0);
    float4 w1 = *reinterpret_cast<const float4*>(wp +  4);
    float4 w2 = *reinterpret_cast<const float4*>(wp +  8);
    float4 w3 = *reinterpret_cast<const float4*>(wp + 12);
    float4 w4 = *reinterpret_cast<const float4*>(wp + 16);
    float4 w5 = *reinterpret_cast<const float4*>(wp + 20);
    float4 w6 = *reinterpret_cast<const float4*>(wp + 24);
    float4 w7 = *reinterpret_cast<const float4*>(wp + 28);

#define PIN4(V) asm volatile("" : "+v"((V).x), "+v"((V).y), "+v"((V).z), "+v"((V).w))
    PIN4(q0); PIN4(q1); PIN4(q2); PIN4(q3);
    PIN4(q4); PIN4(q5); PIN4(q6); PIN4(q7);
    PIN4(w0); PIN4(w1); PIN4(w2); PIN4(w3);
    PIN4(w4); PIN4(w5); PIN4(w6); PIN4(w7);
#undef PIN4

#define ACC4(QV, WV, SV) { float d_; \
    d_ = (QV).x - (SV).x; sc = fmaf((WV).x, fabsf(d_), sc); sq = fmaf(d_, d_, sq); \
    d_ = (QV).y - (SV).y; sc = fmaf((WV).y, fabsf(d_), sc); sq = fmaf(d_, d_, sq); \
    d_ = (QV).z - (SV).z; sc = fmaf((WV).z, fabsf(d_), sc); sq = fmaf(d_, d_, sq); \
    d_ = (QV).w - (SV).w; sc = fmaf((WV).w, fabsf(d_), sc); sq = fmaf(d_, d_, sq); }

    const int sbase = dseg * 36;

    for (int pass = 0; pass < NPASS; ++pass) {
        __syncthreads();   // prev pass: sp reads + praw reduce complete

        // ---- stage 10 support rows (coalesced read -> segmented LDS) ----
        const float4* sg = reinterpret_cast<const float4*>(
            support + (size_t)pass * SCHUNK * DN);
        for (int i = tid; i < SCHUNK * 128; i += BLK) {
            const int row = i >> 7, c4 = i & 127;
            *reinterpret_cast<float4*>(
                sp + row * SROW + 36 * (c4 >> 3) + 4 * (c4 & 7)) = sg[i];
        }
        __syncthreads();

        // ---- hot loop: NO cross-lane ops, NO atomics, 1 b64 write/sl ----
#pragma unroll 5
        for (int sl = 0; sl < SCHUNK; ++sl) {
            const float* sr = sp + sl * SROW + sbase;
            const float4 s0 = *reinterpret_cast<const float4*>(sr +  0);
            const float4 s1 = *reinterpret_cast<const float4*>(sr +  4);
            const float4 s2 = *reinterpret_cast<const float4*>(sr +  8);
            const float4 s3 = *reinterpret_cast<const float4*>(sr + 12);
            const float4 s4 = *reinterpret_cast<const float4*>(sr + 16);
            const float4 s5 = *reinterpret_cast<const float4*>(sr + 20);
            const float4 s6 = *reinterpret_cast<const float4*>(sr + 24);
            const float4 s7 = *reinterpret_cast<const float4*>(sr + 28);

            float sc = 0.0f, sq = 0.0f;
            ACC4(q0, w0, s0) ACC4(q1, w1, s1)
            ACC4(q2, w2, s2) ACC4(q3, w3, s3)
            ACC4(q4, w4, s4) ACC4(q5, w5, s5)
            ACC4(q6, w6, s6) ACC4(q7, w7, s7)

            praw[(sl * QT + ql) * PRW + dseg] = make_float2(sc, sq);
        }
        __syncthreads();

        // ---- per-pass reduce over dseg: fixed order, deterministic ----
        if (tid < SCHUNK * QT) {           // 160 threads
            const int sl = tid >> 4, qq = tid & 15;
            const float2* r = &praw[(sl * QT + qq) * PRW];
            float sc = 0.0f, sq = 0.0f;
#pragma unroll
            for (int d = 0; d < 16; ++d) { sc += r[d].x; sq += r[d].y; }
            part[qq * PSTR + pass * SCHUNK + sl] = make_float2(sc, sq);
        }
    }
#undef ACC4
    __syncthreads();   // all part[] writes visible

    // ---- epilogue: 8 half-wave groups; group g = queries g, g+8 ----
    const int grp  = tid >> 5;
    const int s32  = tid & 31;
    const bool valid = (s32 < SN);
    const int  si  = valid ? s32 : 0;

    float dy = 0.0f;
    if (valid)
        dy = support_y[s32] - 1.0f / (1.0f + expf(-support_pr[s32]));

    const int ns = num_samples[0];
    const float ascale = fabsf(adj_scale[ns - 1]);
    const float abias  = adj_bias[ns - 1];

#pragma unroll
    for (int it = 0; it < 2; ++it) {
        const int qloc = grp + 8 * it;
        const int qg   = blockIdx.x * QT + qloc;
        const float2 pr = part[qloc * PSTR + si];

        float scv = valid ? pr.x : -1e30f;
        float ssv = valid ? pr.y : 0.0f;

        float m = scv;
#pragma unroll
        for (int off = 16; off >= 1; off >>= 1)
            m = fmaxf(m, __shfl_xor(m, off));

        float e   = valid ? expf(scv - m) : 0.0f;
        float den = e;
        float num = dy * e;
        float l2  = valid ? sqrtf(ssv) : 0.0f;
#pragma unroll
        for (int off = 16; off >= 1; off >>= 1) {
            den += __shfl_xor(den, off);
            num += __shfl_xor(num, off);
            l2  += __shfl_xor(l2,  off);
        }

        if (s32 == 0) {
            out[qg]      = num / den * ascale + abias + query_pr[qg];
            out[QN + qg] = l2 * (1.0f / (float)SN);
        }
    }
}

extern "C" void kernel_launch(void* const* d_in, const int* in_sizes, int n_in,
                              void* d_out, int out_size, void* d_ws, size_t ws_size,
                              hipStream_t stream)
{
    const float* query      = (const float*)d_in[0];
    const float* support    = (const float*)d_in[1];
    const float* support_y  = (const float*)d_in[2];
    const float* support_pr = (const float*)d_in[3];
    const float* query_pr   = (const float*)d_in[4];
    const float* fc1_w      = (const float*)d_in[5];
    // d_in[6] = fc1_b: cancels in softmax, unused
    const float* adj_scale  = (const float*)d_in[7];
    const float* adj_bias   = (const float*)d_in[8];
    const int*   num_s      = (const int*)d_in[9];
    float* out = (float*)d_out;

    dim3 grid(QN / QT);      // 512 blocks, 3 per CU (LDS 48.9 KB)
    hipLaunchKernelGGL(resus_one, grid, dim3(BLK), 0, stream,
                       query, support, support_y, support_pr, query_pr,
                       fc1_w, adj_scale, adj_bias, num_s, out);
}

// Round 13
// 96.848 us; speedup vs baseline: 1.9669x; 1.9669x over previous
//
#include <hip/hip_runtime.h>
#include <math.h>

// RESUS_NN_2327872274812: Q=8192, S=30, D=512.  FP32-exact, deterministic.
// r13 = r12's shuffle-free experiment, UN-confounded:
//  - launch_bounds(256,2) (r12's ",3" squeezed VGPR to 84 -> pins spilled
//    INSIDE the hot loop -> 205 MB scratch FETCH storm)
//  - praw as two float arrays, stride 17: write bank = (17*ql+dseg)%32,
//    ~2-way = free (r12's float2/b64 layout was 4-way on 16 bank-pairs,
//    245K conflicts)
//  - otherwise identical to r11 (pinned q/w regs, seg-padded LDS support),
//    minus the hot-loop shuffles whose lgkmcnt(0) drains are the theory
//    under test.
// thread = (ql 0..15, dseg 0..15): query ql, 32-float d-slice dseg.

#define QN 8192
#define SN 30
#define DN 512
#define BLK 256
#define QT 16            // queries per block
#define SCHUNK 10        // support rows per pass
#define NPASS 3
#define SROW 580         // floats per LDS support row (16 segs * 36 + 4)
#define PRW 17           // praw ql-dim stride (floats)
#define PSTR 31          // final part row stride (float2)

__global__ __launch_bounds__(BLK, 2)
void resus_one(const float* __restrict__ query,      // [Q][D]
               const float* __restrict__ support,    // [S][D]
               const float* __restrict__ support_y,  // [S]
               const float* __restrict__ support_pr, // [S]
               const float* __restrict__ query_pr,   // [Q]
               const float* __restrict__ fc1_w,      // [D]
               const float* __restrict__ adj_scale,  // [30]
               const float* __restrict__ adj_bias,   // [30]
               const int*   __restrict__ num_samples,// [1]
               float* __restrict__ out)              // [2*Q]
{
    __shared__ float  sp[SCHUNK * SROW];          // 23,200 B
    __shared__ float  praw_sc[SCHUNK * QT * PRW]; // 10,880 B
    __shared__ float  praw_sq[SCHUNK * QT * PRW]; // 10,880 B
    __shared__ float2 part[QT * PSTR];            //  3,968 B  total 48,928 B

    const int tid  = threadIdx.x;
    const int ql   = tid & 15;                // query slot (lane-fast)
    const int dseg = tid >> 4;                // 32-float d-segment
    const int q    = blockIdx.x * QT + ql;

    // ---- one-time: q + w slices into named regs, then PIN (r11-proven) ----
    const float* qp = query + (size_t)q * DN + dseg * 32;
    float4 q0 = *reinterpret_cast<const float4*>(qp +  0);
    float4 q1 = *reinterpret_cast<const float4*>(qp +  4);
    float4 q2 = *reinterpret_cast<const float4*>(qp +  8);
    float4 q3 = *reinterpret_cast<const float4*>(qp + 12);
    float4 q4 = *reinterpret_cast<const float4*>(qp + 16);
    float4 q5 = *reinterpret_cast<const float4*>(qp + 20);
    float4 q6 = *reinterpret_cast<const float4*>(qp + 24);
    float4 q7 = *reinterpret_cast<const float4*>(qp + 28);
    const float* wp = fc1_w + dseg * 32;
    float4 w0 = *reinterpret_cast<const float4*>(wp +  0);
    float4 w1 = *reinterpret_cast<const float4*>(wp +  4);
    float4 w2 = *reinterpret_cast<const float4*>(wp +  8);
    float4 w3 = *reinterpret_cast<const float4*>(wp + 12);
    float4 w4 = *reinterpret_cast<const float4*>(wp + 16);
    float4 w5 = *reinterpret_cast<const float4*>(wp + 20);
    float4 w6 = *reinterpret_cast<const float4*>(wp + 24);
    float4 w7 = *reinterpret_cast<const float4*>(wp + 28);

#define PIN4(V) asm volatile("" : "+v"((V).x), "+v"((V).y), "+v"((V).z), "+v"((V).w))
    PIN4(q0); PIN4(q1); PIN4(q2); PIN4(q3);
    PIN4(q4); PIN4(q5); PIN4(q6); PIN4(q7);
    PIN4(w0); PIN4(w1); PIN4(w2); PIN4(w3);
    PIN4(w4); PIN4(w5); PIN4(w6); PIN4(w7);
#undef PIN4

#define ACC4(QV, WV, SV) { float d_; \
    d_ = (QV).x - (SV).x; sc = fmaf((WV).x, fabsf(d_), sc); sq = fmaf(d_, d_, sq); \
    d_ = (QV).y - (SV).y; sc = fmaf((WV).y, fabsf(d_), sc); sq = fmaf(d_, d_, sq); \
    d_ = (QV).z - (SV).z; sc = fmaf((WV).z, fabsf(d_), sc); sq = fmaf(d_, d_, sq); \
    d_ = (QV).w - (SV).w; sc = fmaf((WV).w, fabsf(d_), sc); sq = fmaf(d_, d_, sq); }

    const int sbase = dseg * 36;
    const int pbase = ql * PRW + dseg;        // praw offset (sl adds QT*PRW)

    for (int pass = 0; pass < NPASS; ++pass) {
        __syncthreads();   // prev pass: sp reads + reduce complete

        // ---- stage 10 support rows (coalesced read -> segmented LDS) ----
        const float4* sg = reinterpret_cast<const float4*>(
            support + (size_t)pass * SCHUNK * DN);
        for (int i = tid; i < SCHUNK * 128; i += BLK) {
            const int row = i >> 7, c4 = i & 127;
            *reinterpret_cast<float4*>(
                sp + row * SROW + 36 * (c4 >> 3) + 4 * (c4 & 7)) = sg[i];
        }
        __syncthreads();

        // ---- hot loop: no shuffles, no atomics, 2 b32 writes per sl ----
#pragma unroll 5
        for (int sl = 0; sl < SCHUNK; ++sl) {
            const float* sr = sp + sl * SROW + sbase;
            const float4 s0 = *reinterpret_cast<const float4*>(sr +  0);
            const float4 s1 = *reinterpret_cast<const float4*>(sr +  4);
            const float4 s2 = *reinterpret_cast<const float4*>(sr +  8);
            const float4 s3 = *reinterpret_cast<const float4*>(sr + 12);
            const float4 s4 = *reinterpret_cast<const float4*>(sr + 16);
            const float4 s5 = *reinterpret_cast<const float4*>(sr + 20);
            const float4 s6 = *reinterpret_cast<const float4*>(sr + 24);
            const float4 s7 = *reinterpret_cast<const float4*>(sr + 28);

            float sc = 0.0f, sq = 0.0f;
            ACC4(q0, w0, s0) ACC4(q1, w1, s1)
            ACC4(q2, w2, s2) ACC4(q3, w3, s3)
            ACC4(q4, w4, s4) ACC4(q5, w5, s5)
            ACC4(q6, w6, s6) ACC4(q7, w7, s7)

            praw_sc[sl * (QT * PRW) + pbase] = sc;
            praw_sq[sl * (QT * PRW) + pbase] = sq;
        }
        __syncthreads();

        // ---- per-pass reduce over dseg: fixed order, deterministic ----
        if (tid < SCHUNK * QT) {           // 160 threads
            const int sl = tid >> 4, qq = tid & 15;
            const float* rc = &praw_sc[(sl * QT + qq) * PRW - qq * PRW + qq * PRW];
            // (simplify: base index)
            const int b = sl * (QT * PRW) + qq * PRW;
            float sc = 0.0f, sq = 0.0f;
#pragma unroll
            for (int d = 0; d < 16; ++d) {
                sc += praw_sc[b + d];
                sq += praw_sq[b + d];
            }
            (void)rc;
            part[qq * PSTR + pass * SCHUNK + sl] = make_float2(sc, sq);
        }
    }
#undef ACC4
    __syncthreads();   // all part[] writes visible

    // ---- epilogue: 8 half-wave groups; group g = queries g, g+8 ----
    const int grp  = tid >> 5;
    const int s32  = tid & 31;
    const bool valid = (s32 < SN);
    const int  si  = valid ? s32 : 0;

    float dy = 0.0f;
    if (valid)
        dy = support_y[s32] - 1.0f / (1.0f + expf(-support_pr[s32]));

    const int ns = num_samples[0];
    const float ascale = fabsf(adj_scale[ns - 1]);
    const float abias  = adj_bias[ns - 1];

#pragma unroll
    for (int it = 0; it < 2; ++it) {
        const int qloc = grp + 8 * it;
        const int qg   = blockIdx.x * QT + qloc;
        const float2 pr = part[qloc * PSTR + si];

        float scv = valid ? pr.x : -1e30f;
        float ssv = valid ? pr.y : 0.0f;

        float m = scv;
#pragma unroll
        for (int off = 16; off >= 1; off >>= 1)
            m = fmaxf(m, __shfl_xor(m, off));

        float e   = valid ? expf(scv - m) : 0.0f;
        float den = e;
        float num = dy * e;
        float l2  = valid ? sqrtf(ssv) : 0.0f;
#pragma unroll
        for (int off = 16; off >= 1; off >>= 1) {
            den += __shfl_xor(den, off);
            num += __shfl_xor(num, off);
            l2  += __shfl_xor(l2,  off);
        }

        if (s32 == 0) {
            out[qg]      = num / den * ascale + abias + query_pr[qg];
            out[QN + qg] = l2 * (1.0f / (float)SN);
        }
    }
}

extern "C" void kernel_launch(void* const* d_in, const int* in_sizes, int n_in,
                              void* d_out, int out_size, void* d_ws, size_t ws_size,
                              hipStream_t stream)
{
    const float* query      = (const float*)d_in[0];
    const float* support    = (const float*)d_in[1];
    const float* support_y  = (const float*)d_in[2];
    const float* support_pr = (const float*)d_in[3];
    const float* query_pr   = (const float*)d_in[4];
    const float* fc1_w      = (const float*)d_in[5];
    // d_in[6] = fc1_b: cancels in softmax, unused
    const float* adj_scale  = (const float*)d_in[7];
    const float* adj_bias   = (const float*)d_in[8];
    const int*   num_s      = (const int*)d_in[9];
    float* out = (float*)d_out;

    dim3 grid(QN / QT);      // 512 blocks, 2 per CU (LDS 48.9 KB)
    hipLaunchKernelGGL(resus_one, grid, dim3(BLK), 0, stream,
                       query, support, support_y, support_pr, query_pr,
                       fc1_w, adj_scale, adj_bias, num_s, out);
}

// Round 14
// 95.100 us; speedup vs baseline: 2.0031x; 1.0184x over previous
//
#include <hip/hip_runtime.h>
#include <math.h>

// RESUS_NN_2327872274812: Q=8192, S=30, D=512.  FP32-exact, deterministic.
// r14 = r13 + ONE change: s-range split across 2x threads (shalf), doubling
// occupancy 2 -> 4 waves/SIMD. r13's wall: total threads (8192*16) allowed
// only 8 waves/CU resident grid-wide -- ds_read->VALU chains at 2 waves/SIMD
// left ~2.3x latency gap vs the pipe-bill model. Same total VALU/DS work,
// spread over 2048 -> 4096 waves.
// thread = (ql 0..15, dseg 0..15, shalf 0..1): query ql, 32-float d-slice,
// 5 support rows per pass (shalf picks which half of the 10-row chunk).

#define QN 8192
#define SN 30
#define DN 512
#define BLK 512
#define QT 16            // queries per block
#define SCHUNK 10        // support rows per pass
#define NPASS 3
#define SROW 580         // floats per LDS support row (16 segs * 36 + 4)
#define PRW 17           // praw ql-dim stride (floats)
#define PSTR 31          // final part row stride (float2)

__global__ __launch_bounds__(BLK, 2)
void resus_one(const float* __restrict__ query,      // [Q][D]
               const float* __restrict__ support,    // [S][D]
               const float* __restrict__ support_y,  // [S]
               const float* __restrict__ support_pr, // [S]
               const float* __restrict__ query_pr,   // [Q]
               const float* __restrict__ fc1_w,      // [D]
               const float* __restrict__ adj_scale,  // [30]
               const float* __restrict__ adj_bias,   // [30]
               const int*   __restrict__ num_samples,// [1]
               float* __restrict__ out)              // [2*Q]
{
    __shared__ float  sp[SCHUNK * SROW];          // 23,200 B
    __shared__ float  praw_sc[SCHUNK * QT * PRW]; // 10,880 B
    __shared__ float  praw_sq[SCHUNK * QT * PRW]; // 10,880 B
    __shared__ float2 part[QT * PSTR];            //  3,968 B  total 48,928 B

    const int tid   = threadIdx.x;
    const int ql    = tid & 15;               // query slot (lane-fast)
    const int dseg  = (tid >> 4) & 15;        // 32-float d-segment
    const int shalf = tid >> 8;               // 0/1: which 5 rows of a chunk
    const int q     = blockIdx.x * QT + ql;

    // ---- one-time: q + w slices into named regs, then PIN (r11-proven) ----
    const float* qp = query + (size_t)q * DN + dseg * 32;
    float4 q0 = *reinterpret_cast<const float4*>(qp +  0);
    float4 q1 = *reinterpret_cast<const float4*>(qp +  4);
    float4 q2 = *reinterpret_cast<const float4*>(qp +  8);
    float4 q3 = *reinterpret_cast<const float4*>(qp + 12);
    float4 q4 = *reinterpret_cast<const float4*>(qp + 16);
    float4 q5 = *reinterpret_cast<const float4*>(qp + 20);
    float4 q6 = *reinterpret_cast<const float4*>(qp + 24);
    float4 q7 = *reinterpret_cast<const float4*>(qp + 28);
    const float* wp = fc1_w + dseg * 32;
    float4 w0 = *reinterpret_cast<const float4*>(wp +  0);
    float4 w1 = *reinterpret_cast<const float4*>(wp +  4);
    float4 w2 = *reinterpret_cast<const float4*>(wp +  8);
    float4 w3 = *reinterpret_cast<const float4*>(wp + 12);
    float4 w4 = *reinterpret_cast<const float4*>(wp + 16);
    float4 w5 = *reinterpret_cast<const float4*>(wp + 20);
    float4 w6 = *reinterpret_cast<const float4*>(wp + 24);
    float4 w7 = *reinterpret_cast<const float4*>(wp + 28);

#define PIN4(V) asm volatile("" : "+v"((V).x), "+v"((V).y), "+v"((V).z), "+v"((V).w))
    PIN4(q0); PIN4(q1); PIN4(q2); PIN4(q3);
    PIN4(q4); PIN4(q5); PIN4(q6); PIN4(q7);
    PIN4(w0); PIN4(w1); PIN4(w2); PIN4(w3);
    PIN4(w4); PIN4(w5); PIN4(w6); PIN4(w7);
#undef PIN4

#define ACC4(QV, WV, SV) { float d_; \
    d_ = (QV).x - (SV).x; sc = fmaf((WV).x, fabsf(d_), sc); sq = fmaf(d_, d_, sq); \
    d_ = (QV).y - (SV).y; sc = fmaf((WV).y, fabsf(d_), sc); sq = fmaf(d_, d_, sq); \
    d_ = (QV).z - (SV).z; sc = fmaf((WV).z, fabsf(d_), sc); sq = fmaf(d_, d_, sq); \
    d_ = (QV).w - (SV).w; sc = fmaf((WV).w, fabsf(d_), sc); sq = fmaf(d_, d_, sq); }

    const int sbase = dseg * 36;
    const int pbase = ql * PRW + dseg;        // praw offset (sl adds QT*PRW)
    const int sl0   = shalf * (SCHUNK / 2);   // 0 or 5

    for (int pass = 0; pass < NPASS; ++pass) {
        __syncthreads();   // prev pass: sp reads + reduce complete

        // ---- stage 10 support rows (coalesced read -> segmented LDS) ----
        const float4* sg = reinterpret_cast<const float4*>(
            support + (size_t)pass * SCHUNK * DN);
        for (int i = tid; i < SCHUNK * 128; i += BLK) {
            const int row = i >> 7, c4 = i & 127;
            *reinterpret_cast<float4*>(
                sp + row * SROW + 36 * (c4 >> 3) + 4 * (c4 & 7)) = sg[i];
        }
        __syncthreads();

        // ---- hot loop: 5 rows per thread, no shuffles, no atomics ----
#pragma unroll
        for (int k = 0; k < SCHUNK / 2; ++k) {
            const int sl = sl0 + k;
            const float* sr = sp + sl * SROW + sbase;
            const float4 s0 = *reinterpret_cast<const float4*>(sr +  0);
            const float4 s1 = *reinterpret_cast<const float4*>(sr +  4);
            const float4 s2 = *reinterpret_cast<const float4*>(sr +  8);
            const float4 s3 = *reinterpret_cast<const float4*>(sr + 12);
            const float4 s4 = *reinterpret_cast<const float4*>(sr + 16);
            const float4 s5 = *reinterpret_cast<const float4*>(sr + 20);
            const float4 s6 = *reinterpret_cast<const float4*>(sr + 24);
            const float4 s7 = *reinterpret_cast<const float4*>(sr + 28);

            float sc = 0.0f, sq = 0.0f;
            ACC4(q0, w0, s0) ACC4(q1, w1, s1)
            ACC4(q2, w2, s2) ACC4(q3, w3, s3)
            ACC4(q4, w4, s4) ACC4(q5, w5, s5)
            ACC4(q6, w6, s6) ACC4(q7, w7, s7)

            praw_sc[sl * (QT * PRW) + pbase] = sc;
            praw_sq[sl * (QT * PRW) + pbase] = sq;
        }
        __syncthreads();

        // ---- per-pass reduce over dseg: fixed order, deterministic ----
        if (tid < SCHUNK * QT) {           // 160 threads
            const int sl = tid >> 4, qq = tid & 15;
            const int b = sl * (QT * PRW) + qq * PRW;
            float sc = 0.0f, sq = 0.0f;
#pragma unroll
            for (int d = 0; d < 16; ++d) {
                sc += praw_sc[b + d];
                sq += praw_sq[b + d];
            }
            part[qq * PSTR + pass * SCHUNK + sl] = make_float2(sc, sq);
        }
    }
#undef ACC4
    __syncthreads();   // all part[] writes visible

    // ---- epilogue: 16 half-wave groups; group g = query g ----
    const int grp  = tid >> 5;                // 0..15
    const int s32  = tid & 31;
    const bool valid = (s32 < SN);
    const int  si  = valid ? s32 : 0;

    float dy = 0.0f;
    if (valid)
        dy = support_y[s32] - 1.0f / (1.0f + expf(-support_pr[s32]));

    const int ns = num_samples[0];
    const float ascale = fabsf(adj_scale[ns - 1]);
    const float abias  = adj_bias[ns - 1];

    const int qg = blockIdx.x * QT + grp;
    const float2 pr = part[grp * PSTR + si];

    float scv = valid ? pr.x : -1e30f;
    float ssv = valid ? pr.y : 0.0f;

    float m = scv;
#pragma unroll
    for (int off = 16; off >= 1; off >>= 1)
        m = fmaxf(m, __shfl_xor(m, off));

    float e   = valid ? expf(scv - m) : 0.0f;
    float den = e;
    float num = dy * e;
    float l2  = valid ? sqrtf(ssv) : 0.0f;
#pragma unroll
    for (int off = 16; off >= 1; off >>= 1) {
        den += __shfl_xor(den, off);
        num += __shfl_xor(num, off);
        l2  += __shfl_xor(l2,  off);
    }

    if (s32 == 0) {
        out[qg]      = num / den * ascale + abias + query_pr[qg];
        out[QN + qg] = l2 * (1.0f / (float)SN);
    }
}

extern "C" void kernel_launch(void* const* d_in, const int* in_sizes, int n_in,
                              void* d_out, int out_size, void* d_ws, size_t ws_size,
                              hipStream_t stream)
{
    const float* query      = (const float*)d_in[0];
    const float* support    = (const float*)d_in[1];
    const float* support_y  = (const float*)d_in[2];
    const float* support_pr = (const float*)d_in[3];
    const float* query_pr   = (const float*)d_in[4];
    const float* fc1_w      = (const float*)d_in[5];
    // d_in[6] = fc1_b: cancels in softmax, unused
    const float* adj_scale  = (const float*)d_in[7];
    const float* adj_bias   = (const float*)d_in[8];
    const int*   num_s      = (const int*)d_in[9];
    float* out = (float*)d_out;

    dim3 grid(QN / QT);      // 512 blocks x 8 waves = 4096 waves = 4/SIMD
    hipLaunchKernelGGL(resus_one, grid, dim3(BLK), 0, stream,
                       query, support, support_y, support_pr, query_pr,
                       fc1_w, adj_scale, adj_bias, num_s, out);
}